// Round 16
// baseline (152.898 us; speedup 1.0000x reference)
//
#include <hip/hip_runtime.h>
#include <stdint.h>

#define NB 2
#define NS 2048
#define NH 32
#define NKV 8
#define ND 128
#define NWIN 1024
#define KVB 32
// scale * log2(e) : scores tracked in exp2 domain
#define SCALE2 (0.08838834764831845f * 1.4426950408889634f)
#define LOG2E 1.4426950408889634f

typedef __bf16 bf16x8 __attribute__((ext_vector_type(8)));
typedef float f32x4 __attribute__((ext_vector_type(4)));
typedef unsigned short u16x4 __attribute__((ext_vector_type(4)));
typedef unsigned short u16x8 __attribute__((ext_vector_type(8)));
typedef unsigned int u32x2 __attribute__((ext_vector_type(2)));

union Frag { u16x8 u; bf16x8 b; u32x2 w[2]; __bf16 e[8]; };
union BF4 { u16x4 u; __bf16 b[4]; };
union BF8 { u16x8 u; __bf16 b[8]; };

__device__ __forceinline__ void gload16(const unsigned short* g, unsigned short* l) {
  __builtin_amdgcn_global_load_lds(
      (const __attribute__((address_space(1))) unsigned int*)g,
      (__attribute__((address_space(3))) unsigned int*)l, 16, 0, 0);
}

// ---------------- pre-pass: K,V fp32 -> bf16 into ws ----------------
__global__ __launch_bounds__(256)
void cvt_kv(const float* __restrict__ k, const float* __restrict__ v,
            unsigned short* __restrict__ kbf, unsigned short* __restrict__ vbf) {
  const int i = blockIdx.x * blockDim.x + threadIdx.x;  // 8 elems/thread
  float4 a0 = ((const float4*)k)[i * 2], a1 = ((const float4*)k)[i * 2 + 1];
  float4 b0 = ((const float4*)v)[i * 2], b1 = ((const float4*)v)[i * 2 + 1];
  BF8 ko, vo;
  ko.b[0] = (__bf16)a0.x; ko.b[1] = (__bf16)a0.y; ko.b[2] = (__bf16)a0.z; ko.b[3] = (__bf16)a0.w;
  ko.b[4] = (__bf16)a1.x; ko.b[5] = (__bf16)a1.y; ko.b[6] = (__bf16)a1.z; ko.b[7] = (__bf16)a1.w;
  vo.b[0] = (__bf16)b0.x; vo.b[1] = (__bf16)b0.y; vo.b[2] = (__bf16)b0.z; vo.b[3] = (__bf16)b0.w;
  vo.b[4] = (__bf16)b1.x; vo.b[5] = (__bf16)b1.y; vo.b[6] = (__bf16)b1.z; vo.b[7] = (__bf16)b1.w;
  ((u16x8*)kbf)[i] = ko.u;
  ((u16x8*)vbf)[i] = vo.u;
}

// ---------------- main: R12 structure + ones-MFMA l-sum ----------------
// R12 verbatim (4 waves = 4 heads of one KV group; 33-tile balanced paired
// bands; grid 768; descending tiles; lane-local defer-max; folded m-in-bias
// softmax; PV depth-4 tr-read pipeline) with ONE change:
//  * l-sum by MFMA: lacc = mfma(ones16x32, pb, lacc). B-frag gathers all 64
//    lanes' pb -> C[row][q=l15] = FULL 32-key tile sum (cross-lane reduced in
//    the matrix pipe). Replaces 8 VALU adds/half/tile + epilogue shuffles.
//    Rescale branch scales lacc vector. l_final = lacc[0].
__global__ __launch_bounds__(256)
void attn_gqa(const unsigned short* __restrict__ kbf,
              const unsigned short* __restrict__ vbf,
              const float* __restrict__ qg, float* __restrict__ og) {
  __shared__ unsigned short k_lds[2][KVB * 128];   // 2 x 8 KB
  __shared__ unsigned short v_lds[2][KVB * 128];   // 2 x 8 KB

  const int tid = threadIdx.x;
  const int w = tid >> 6;           // 0..3 = head within KV group
  const int lane = tid & 63;
  const int l15 = lane & 15;
  const int lg = lane >> 4;

  const int bid = blockIdx.x;
  const int hkv = bid & 7;
  const int rest = bid >> 3;        // 0..95
  const int b = (rest >= 48) ? 1 : 0;
  const int slot = rest - b * 48;   // 0..47
  const int h = hkv * 4 + w;
  const float slope2 = exp2f(-0.25f * (float)(h + 1)) * LOG2E;

  // ---- per-lane staging source offsets (elems within (b,hkv) panel) ----
  int koff_e[2], voff_e[2];
#pragma unroll
  for (int i = 0; i < 2; ++i) {
    const int rk = (w * 2 + i) * 4 + lg;                   // LDS K row
    const int c = l15;                                     // 16B chunk
    const int sig = ((rk >> 2) & 3) * 8 + ((rk >> 4) & 1) * 4 + (rk & 3);
    koff_e[i] = sig * (NKV * ND) + ((c ^ (rk & 7)) * 8);
    const int e0 = (w * 2 + i) * 512 + lane * 8;           // LDS V elem
    const int sx0 = e0 & 15;
    const int vj = (e0 >> 4) & 3;
    const int vg_ = (e0 >> 6) & 3;
    const int s1 = (e0 >> 8) & 1;
    const int scv = (e0 >> 9) & 7;
    voff_e[i] = (vg_ * 8 + s1 * 4 + vj) * (NKV * ND) + scv * 16 + sx0;
  }
  const unsigned short* kpan = kbf + (size_t)b * NS * (NKV * ND) + hkv * ND;
  const unsigned short* vpan = vbf + (size_t)b * NS * (NKV * ND) + hkv * ND;

  auto stage = [&](int t, int buf) {
    const size_t eb = (size_t)(t * KVB) * (NKV * ND);
#pragma unroll
    for (int i = 0; i < 2; ++i) {
      gload16(kpan + eb + koff_e[i], &k_lds[buf][(w * 2 + i) * 512]);
      gload16(vpan + eb + voff_e[i], &v_lds[buf][(w * 2 + i) * 512]);
    }
  };

  Frag ones;
#pragma unroll
  for (int j = 0; j < 8; ++j) ones.e[j] = (__bf16)1.0f;

  auto run_band = [&](int q0) {
    const int qiA = q0 + l15;
    const int qiB = qiA + 16;

    // ---- Q fragments (fp32 -> bf16) ----
    u16x8 qfA[4], qfB[4];
#pragma unroll
    for (int half = 0; half < 2; ++half) {
      const int qi = half ? qiB : qiA;
      const float* qp = qg + (size_t)(b * NS + qi) * (NH * ND) + h * ND;
#pragma unroll
      for (int ks = 0; ks < 4; ++ks) {
        const int dbase = ks * 32 + lg * 8;
        float4 f0 = *(const float4*)(qp + dbase);
        float4 f1 = *(const float4*)(qp + dbase + 4);
        Frag q_;
        q_.e[0] = (__bf16)f0.x; q_.e[1] = (__bf16)f0.y;
        q_.e[2] = (__bf16)f0.z; q_.e[3] = (__bf16)f0.w;
        q_.e[4] = (__bf16)f1.x; q_.e[5] = (__bf16)f1.y;
        q_.e[6] = (__bf16)f1.z; q_.e[7] = (__bf16)f1.w;
        if (half) qfB[ks] = q_.u; else qfA[ks] = q_.u;
      }
    }

    float mA = 0.f, mB = 0.f;                       // m=0: diagonal key valid
    f32x4 laccA = {0.f, 0.f, 0.f, 0.f}, laccB = {0.f, 0.f, 0.f, 0.f};
    f32x4 accA[8], accB[8];
#pragma unroll
    for (int c = 0; c < 8; ++c) {
      accA[c][0] = 0.f; accA[c][1] = 0.f; accA[c][2] = 0.f; accA[c][3] = 0.f;
      accB[c][0] = 0.f; accB[c][1] = 0.f; accB[c][2] = 0.f; accB[c][3] = 0.f;
    }

    const int t0 = (q0 >= NWIN) ? ((q0 - NWIN) >> 5) : 0;
    const int t1 = q0 >> 5;

    int cur = 0;
    stage(t1, 0);   // DESCENDING: near-diagonal tile first

    for (int t = t1; t >= t0; --t) {
      const int kvbase = t * KVB;
      if (t > t0) {
        stage(t - 1, cur ^ 1);
        asm volatile("s_waitcnt vmcnt(4)" ::: "memory");   // tile t's 4 loads done
      } else {
        asm volatile("s_waitcnt vmcnt(0)" ::: "memory");
      }
      __builtin_amdgcn_s_barrier();                        // all waves' t loads done

      // interior: masking provably inactive for all 32 rows of the band
      const bool interior = (kvbase + 31 <= q0) && (kvbase >= q0 + 31 - NWIN);

      // ---- QK^T (swapped): K-frags shared by both halves ----
      f32x4 sA[2], sB[2];
#pragma unroll
      for (int f = 0; f < 2; ++f) {
        sA[f][0] = 0.f; sA[f][1] = 0.f; sA[f][2] = 0.f; sA[f][3] = 0.f;
        sB[f][0] = 0.f; sB[f][1] = 0.f; sB[f][2] = 0.f; sB[f][3] = 0.f;
      }
      const int xo = (l15 & 7) << 4;
      __builtin_amdgcn_s_setprio(1);
#pragma unroll
      for (int ks = 0; ks < 4; ++ks) {
        const int db2 = ks * 64 + lg * 16;
        Frag qa, qb;
        qa.u = qfA[ks]; qb.u = qfB[ks];
#pragma unroll
        for (int f = 0; f < 2; ++f) {
          Frag kb;
          kb.u = *(const u16x8*)((const char*)&k_lds[cur][0] +
                                 (((f * 16 + l15) * 256 + db2) ^ xo));
          sA[f] = __builtin_amdgcn_mfma_f32_16x16x32_bf16(kb.b, qa.b, sA[f], 0, 0, 0);
          sB[f] = __builtin_amdgcn_mfma_f32_16x16x32_bf16(kb.b, qb.b, sB[f], 0, 0, 0);
        }
      }
      __builtin_amdgcn_s_setprio(0);

      // ---- lane-local online softmax per half (x = s*SCALE2 + bias - m_r) ----
      Frag pbA, pbB;
      auto softmax_half = [&](const f32x4* s, int dbse, float& m_r, f32x4& lacc,
                              f32x4* acc, Frag& pb) {
        float x[2][4];
        if (interior) {
          const float ab2 = fmaf(-slope2, (float)dbse, -m_r);
#pragma unroll
          for (int f = 0; f < 2; ++f)
#pragma unroll
            for (int r = 0; r < 4; ++r)
              x[f][r] = fmaf(s[f][r], SCALE2,
                             fmaf(slope2, (float)(f * 4 + r), ab2));
        } else {
#pragma unroll
          for (int f = 0; f < 2; ++f)
#pragma unroll
            for (int r = 0; r < 4; ++r) {
              const int d = dbse - (f * 4 + r);           // qi - j
              const float val = fmaf(s[f][r], SCALE2, -slope2 * (float)d) - m_r;
              x[f][r] = ((unsigned)d <= (unsigned)NWIN) ? val : -1e30f;
            }
        }
        float tm = fmaxf(fmaxf(fmaxf(x[0][0], x[0][1]), x[0][2]),
                         fmaxf(fmaxf(x[0][3], x[1][0]), x[1][1]));
        tm = fmaxf(tm, fmaxf(x[1][2], x[1][3]));
        // common path: NO cross-lane ops; P <= 2^8 is bf16/fp32-safe.
        if (!__all(tm <= 8.0f)) {   // rare; wave-uniform branch
          tm = fmaxf(tm, __shfl_xor(tm, 16, 64));
          tm = fmaxf(tm, __shfl_xor(tm, 32, 64));
          const float delta = fmaxf(tm, 0.f);
          const float fac = __builtin_amdgcn_exp2f(-delta);
          m_r += delta;
          lacc = lacc * fac;
#pragma unroll
          for (int c = 0; c < 8; ++c) acc[c] = acc[c] * fac;
#pragma unroll
          for (int f = 0; f < 2; ++f)
#pragma unroll
            for (int r = 0; r < 4; ++r) x[f][r] -= delta;
        }
#pragma unroll
        for (int f = 0; f < 2; ++f)
#pragma unroll
          for (int r = 0; r < 4; ++r)
            pb.e[f * 4 + r] = (__bf16)__builtin_amdgcn_exp2f(x[f][r]);
      };
      softmax_half(sA, qiA - kvbase - lg * 8, mA, laccA, accA, pbA);
      softmax_half(sB, qiB - kvbase - lg * 8, mB, laccB, accB, pbB);

      // ---- PV (swapped), depth-4 pipelined tr-reads; l-sum via ones-MFMA ----
      Frag vb4[4];
      const unsigned int vbase = (unsigned int)(uintptr_t)(&v_lds[cur][0]) + lane * 8;
#pragma unroll
      for (int cp = 0; cp < 4; ++cp) {
        const unsigned int a = vbase + cp * 1024;
        asm volatile("ds_read_b64_tr_b16 %0, %1" : "=v"(vb4[cp].w[0]) : "v"(a));
        asm volatile("ds_read_b64_tr_b16 %0, %1 offset:512" : "=v"(vb4[cp].w[1]) : "v"(a));
      }
      __builtin_amdgcn_s_setprio(1);
      // l-sum: C[row][q=l15] = sum over ALL 32 keys of P (cross-lane via B-frag)
      laccA = __builtin_amdgcn_mfma_f32_16x16x32_bf16(ones.b, pbA.b, laccA, 0, 0, 0);
      laccB = __builtin_amdgcn_mfma_f32_16x16x32_bf16(ones.b, pbB.b, laccB, 0, 0, 0);
#pragma unroll
      for (int c = 0; c < 8; ++c) {
        if (c == 5)      asm volatile("s_waitcnt lgkmcnt(4)" ::: "memory");
        else if (c == 6) asm volatile("s_waitcnt lgkmcnt(2)" ::: "memory");
        else if (c == 7) asm volatile("s_waitcnt lgkmcnt(0)" ::: "memory");
        else             asm volatile("s_waitcnt lgkmcnt(6)" ::: "memory");
        __builtin_amdgcn_sched_barrier(0);
        accA[c] = __builtin_amdgcn_mfma_f32_16x16x32_bf16(vb4[c & 3].b, pbA.b, accA[c], 0, 0, 0);
        accB[c] = __builtin_amdgcn_mfma_f32_16x16x32_bf16(vb4[c & 3].b, pbB.b, accB[c], 0, 0, 0);
        if (c < 4) {
          const unsigned int a2 = vbase + (c + 4) * 1024;
          asm volatile("ds_read_b64_tr_b16 %0, %1" : "=v"(vb4[c].w[0]) : "v"(a2));
          asm volatile("ds_read_b64_tr_b16 %0, %1 offset:512" : "=v"(vb4[c].w[1]) : "v"(a2));
        }
      }
      __builtin_amdgcn_s_setprio(0);
      __builtin_amdgcn_sched_barrier(0);
      __builtin_amdgcn_s_barrier();      // all waves done reading buf[cur]
      cur ^= 1;
    }

    // ---- epilogue: l = lacc[0] (already cross-lane reduced), O = acc/l ----
    {
      const float inv = 1.0f / laccA[0];
      float* op = og + (size_t)(b * NS + qiA) * (NH * ND) + h * ND + lg * 4;
#pragma unroll
      for (int c = 0; c < 8; ++c) { f32x4 o = accA[c] * inv; *(f32x4*)(op + c * 16) = o; }
    }
    {
      const float inv = 1.0f / laccB[0];
      float* op = og + (size_t)(b * NS + qiB) * (NH * ND) + h * ND + lg * 4;
#pragma unroll
      for (int c = 0; c < 8; ++c) { f32x4 o = accB[c] * inv; *(f32x4*)(op + c * 16) = o; }
    }
  };

  if (slot < 32) {
    run_band((slot + 32) * 32);                   // long bands: 33 tiles
  } else {
    const int s = slot - 32;                      // paired shorts: (s+1)+(32-s)=33
    run_band(s * 32);
    run_band((31 - s) * 32);
  }
}

// ---------------- fallback (R6, 154us): used when ws too small ----------------
__global__ __launch_bounds__(256, 2)
void attn_fb(const float* __restrict__ qg, const float* __restrict__ kg,
             const float* __restrict__ vg, float* __restrict__ og) {
  __shared__ unsigned short k_lds[64 * 128];
  __shared__ unsigned short v_lds[64 * 128];
  const int tid = threadIdx.x;
  const int w = tid >> 6;
  const int lane = tid & 63;
  const int l15 = lane & 15;
  const int lg = lane >> 4;
  const int bid = blockIdx.x;
  const int h = bid & 31;
  const int qt = 31 - ((bid >> 5) & 31);
  const int b = bid >> 10;
  const int hkv = h >> 2;
  const float slope2 = exp2f(-0.25f * (float)(h + 1)) * LOG2E;
  const int q0 = qt * 64;
  const int qi = q0 + w * 16 + l15;
  u16x8 qf[4];
  {
    const float* qp = qg + (size_t)(b * NS + qi) * (NH * ND) + h * ND;
#pragma unroll
    for (int ks = 0; ks < 4; ++ks) {
      const int dbase = ks * 32 + lg * 8;
      float4 f0 = *(const float4*)(qp + dbase);
      float4 f1 = *(const float4*)(qp + dbase + 4);
      Frag q_;
      q_.e[0] = (__bf16)f0.x; q_.e[1] = (__bf16)f0.y;
      q_.e[2] = (__bf16)f0.z; q_.e[3] = (__bf16)f0.w;
      q_.e[4] = (__bf16)f1.x; q_.e[5] = (__bf16)f1.y;
      q_.e[6] = (__bf16)f1.z; q_.e[7] = (__bf16)f1.w;
      qf[ks] = q_.u;
    }
  }
  float m_r = -1e30f, l_r = 0.f;
  f32x4 acc[8];
#pragma unroll
  for (int c = 0; c < 8; ++c) { acc[c][0] = 0.f; acc[c][1] = 0.f; acc[c][2] = 0.f; acc[c][3] = 0.f; }
  const int srow = tid >> 5;
  const int sdb = (tid & 31) * 4;
  const int sc = sdb >> 4;
  const int sx = sdb & 15;
  float4 kreg[8], vreg[8];
  const int t0 = (q0 >= NWIN) ? ((q0 - NWIN) >> 6) : 0;
  const int t1 = q0 >> 6;
  auto load_tile = [&](int t) {
    const int kvbase = t * 64;
#pragma unroll
    for (int it = 0; it < 8; ++it) {
      const size_t go = (size_t)(b * NS + kvbase + it * 8 + srow) * (NKV * ND) + hkv * ND + sdb;
      kreg[it] = *(const float4*)(kg + go);
      vreg[it] = *(const float4*)(vg + go);
    }
  };
  load_tile(t0);
  for (int t = t0; t <= t1; ++t) {
    const int kvbase = t * 64;
    __syncthreads();
#pragma unroll
    for (int it = 0; it < 8; ++it) {
      const int row = it * 8 + srow;
      BF4 ku, vu;
      ku.b[0] = (__bf16)kreg[it].x; ku.b[1] = (__bf16)kreg[it].y;
      ku.b[2] = (__bf16)kreg[it].z; ku.b[3] = (__bf16)kreg[it].w;
      vu.b[0] = (__bf16)vreg[it].x; vu.b[1] = (__bf16)vreg[it].y;
      vu.b[2] = (__bf16)vreg[it].z; vu.b[3] = (__bf16)vreg[it].w;
      const int rk = ((row & 4) << 3) | ((row & 56) >> 1) | (row & 3);
      const int kb = (rk * 256 + sdb * 2) ^ ((rk & 7) << 4);
      *(u16x4*)((char*)k_lds + kb) = ku.u;
      const int s2 = ((row >> 5) << 1) | ((row >> 2) & 1);
      const int vi = sc * 1024 + s2 * 256 + ((row >> 3) & 3) * 64 + (row & 3) * 16 + sx;
      *(u16x4*)(&v_lds[vi]) = vu.u;
    }
    __syncthreads();
    if (t < t1) load_tile(t + 1);
    f32x4 s[4];
#pragma unroll
    for (int f = 0; f < 4; ++f) { s[f][0] = 0.f; s[f][1] = 0.f; s[f][2] = 0.f; s[f][3] = 0.f; }
    const int xo = (l15 & 7) << 4;
#pragma unroll
    for (int ks = 0; ks < 4; ++ks) {
      const int db2 = ks * 64 + lg * 16;
      Frag qa; qa.u = qf[ks];
#pragma unroll
      for (int f = 0; f < 4; ++f) {
        Frag kb;
        kb.u = *(u16x8*)((char*)k_lds + (((f * 16 + l15) * 256 + db2) ^ xo));
        s[f] = __builtin_amdgcn_mfma_f32_16x16x32_bf16(kb.b, qa.b, s[f], 0, 0, 0);
      }
    }
    const int dbse = qi - kvbase - lg * 8;
    float sv[4][4];
#pragma unroll
    for (int f = 0; f < 4; ++f) {
#pragma unroll
      for (int r = 0; r < 4; ++r) {
        const int koff = ((f & 1) << 5) + ((f >> 1) << 2) + r;
        const int d = dbse - koff;
        const float val = fmaf(s[f][r], SCALE2, -slope2 * (float)d);
        sv[f][r] = ((unsigned)d <= (unsigned)NWIN) ? val : -1e30f;
      }
    }
    float tm = fmaxf(fmaxf(sv[0][0], sv[0][1]), fmaxf(sv[0][2], sv[0][3]));
#pragma unroll
    for (int f = 1; f < 4; ++f)
      tm = fmaxf(tm, fmaxf(fmaxf(sv[f][0], sv[f][1]), fmaxf(sv[f][2], sv[f][3])));
    tm = fmaxf(tm, __shfl_xor(tm, 16, 64));
    tm = fmaxf(tm, __shfl_xor(tm, 32, 64));
    const float newm = fmaxf(m_r, tm);
    const float fac = __builtin_amdgcn_exp2f(m_r - newm);
    m_r = newm;
    float rs = 0.f;
    Frag pb0, pb1;
#pragma unroll
    for (int f = 0; f < 4; ++f) {
      float e0 = __builtin_amdgcn_exp2f(sv[f][0] - m_r);
      float e1 = __builtin_amdgcn_exp2f(sv[f][1] - m_r);
      float e2 = __builtin_amdgcn_exp2f(sv[f][2] - m_r);
      float e3 = __builtin_amdgcn_exp2f(sv[f][3] - m_r);
      rs += (e0 + e1) + (e2 + e3);
      const int base = (f >> 1) * 4;
      if (f & 1) {
        pb1.e[base + 0] = (__bf16)e0; pb1.e[base + 1] = (__bf16)e1;
        pb1.e[base + 2] = (__bf16)e2; pb1.e[base + 3] = (__bf16)e3;
      } else {
        pb0.e[base + 0] = (__bf16)e0; pb0.e[base + 1] = (__bf16)e1;
        pb0.e[base + 2] = (__bf16)e2; pb0.e[base + 3] = (__bf16)e3;
      }
    }
    rs += __shfl_xor(rs, 16, 64);
    rs += __shfl_xor(rs, 32, 64);
    l_r = l_r * fac + rs;
#pragma unroll
    for (int c = 0; c < 8; ++c) acc[c] = acc[c] * fac;
    const unsigned int vbase = (unsigned int)(uintptr_t)(&v_lds[0]) + lane * 8;
#pragma unroll
    for (int c = 0; c < 8; ++c) {
      u32x2 r0, r1, r2, r3;
      const unsigned int a = vbase + c * 2048;
      asm volatile("ds_read_b64_tr_b16 %0, %1" : "=v"(r0) : "v"(a));
      asm volatile("ds_read_b64_tr_b16 %0, %1 offset:512" : "=v"(r1) : "v"(a));
      asm volatile("ds_read_b64_tr_b16 %0, %1 offset:1024" : "=v"(r2) : "v"(a));
      asm volatile("ds_read_b64_tr_b16 %0, %1 offset:1536" : "=v"(r3) : "v"(a));
      asm volatile("s_waitcnt lgkmcnt(0)" ::: "memory");
      __builtin_amdgcn_sched_barrier(0);
      Frag vb0, vb1;
      vb0.w[0] = r0; vb0.w[1] = r1;
      vb1.w[0] = r2; vb1.w[1] = r3;
      acc[c] = __builtin_amdgcn_mfma_f32_16x16x32_bf16(vb0.b, pb0.b, acc[c], 0, 0, 0);
      acc[c] = __builtin_amdgcn_mfma_f32_16x16x32_bf16(vb1.b, pb1.b, acc[c], 0, 0, 0);
    }
  }
  const float inv = 1.0f / l_r;
  float* op = og + (size_t)(b * NS + qi) * (NH * ND) + h * ND + lg * 4;
#pragma unroll
  for (int c = 0; c < 8; ++c) { f32x4 o = acc[c] * inv; *(f32x4*)(op + c * 16) = o; }
}

extern "C" void kernel_launch(void* const* d_in, const int* in_sizes, int n_in,
                              void* d_out, int out_size, void* d_ws, size_t ws_size,
                              hipStream_t stream) {
  (void)in_sizes; (void)n_in; (void)out_size;
  const float* q = (const float*)d_in[0];
  const float* k = (const float*)d_in[1];
  const float* v = (const float*)d_in[2];
  float* out = (float*)d_out;
  const size_t kv_elems = (size_t)NB * NS * NKV * ND;       // 4M elems each
  const size_t need = 2 * kv_elems * sizeof(unsigned short); // 16 MB
  if (ws_size >= need) {
    unsigned short* kbf = (unsigned short*)d_ws;
    unsigned short* vbf = kbf + kv_elems;
    cvt_kv<<<dim3((unsigned)(kv_elems / 8 / 256)), dim3(256), 0, stream>>>(k, v, kbf, vbf);
    attn_gqa<<<dim3(NB * NKV * 48), dim3(256), 0, stream>>>(kbf, vbf, q, out);
  } else {
    attn_fb<<<dim3(NB * NH * (NS / 64)), dim3(256), 0, stream>>>(q, k, v, out);
  }
}

// Round 17
// 115.318 us; speedup vs baseline: 1.3259x; 1.3259x over previous
//
#include <hip/hip_runtime.h>
#include <stdint.h>

#define NB 2
#define NS 2048
#define NH 32
#define NKV 8
#define ND 128
#define NWIN 1024
#define KVB 32
// scale * log2(e) : scores tracked in exp2 domain
#define SCALE2 (0.08838834764831845f * 1.4426950408889634f)
#define LOG2E 1.4426950408889634f

typedef __bf16 bf16x8 __attribute__((ext_vector_type(8)));
typedef float f32x4 __attribute__((ext_vector_type(4)));
typedef unsigned short u16x4 __attribute__((ext_vector_type(4)));
typedef unsigned short u16x8 __attribute__((ext_vector_type(8)));
typedef unsigned int u32x2 __attribute__((ext_vector_type(2)));

union Frag { u16x8 u; bf16x8 b; u32x2 w[2]; __bf16 e[8]; };
union BF4 { u16x4 u; __bf16 b[4]; };
union BF8 { u16x8 u; __bf16 b[8]; };

__device__ __forceinline__ void gload16(const unsigned short* g, unsigned short* l) {
  __builtin_amdgcn_global_load_lds(
      (const __attribute__((address_space(1))) unsigned int*)g,
      (__attribute__((address_space(3))) unsigned int*)l, 16, 0, 0);
}

// ---------------- pre-pass: K,V fp32 -> bf16 into ws ----------------
__global__ __launch_bounds__(256)
void cvt_kv(const float* __restrict__ k, const float* __restrict__ v,
            unsigned short* __restrict__ kbf, unsigned short* __restrict__ vbf) {
  const int i = blockIdx.x * blockDim.x + threadIdx.x;  // 8 elems/thread
  float4 a0 = ((const float4*)k)[i * 2], a1 = ((const float4*)k)[i * 2 + 1];
  float4 b0 = ((const float4*)v)[i * 2], b1 = ((const float4*)v)[i * 2 + 1];
  BF8 ko, vo;
  ko.b[0] = (__bf16)a0.x; ko.b[1] = (__bf16)a0.y; ko.b[2] = (__bf16)a0.z; ko.b[3] = (__bf16)a0.w;
  ko.b[4] = (__bf16)a1.x; ko.b[5] = (__bf16)a1.y; ko.b[6] = (__bf16)a1.z; ko.b[7] = (__bf16)a1.w;
  vo.b[0] = (__bf16)b0.x; vo.b[1] = (__bf16)b0.y; vo.b[2] = (__bf16)b0.z; vo.b[3] = (__bf16)b0.w;
  vo.b[4] = (__bf16)b1.x; vo.b[5] = (__bf16)b1.y; vo.b[6] = (__bf16)b1.z; vo.b[7] = (__bf16)b1.w;
  ((u16x8*)kbf)[i] = ko.u;
  ((u16x8*)vbf)[i] = vo.u;
}

// ---------------- main: GQA-grouped, latency-flattened (R12, session best) --
// 4 waves = 4 heads of one KV group; 33-tile balanced paired bands; grid 768;
// descending tiles; lane-local defer-max; folded m-in-bias softmax; lane-
// partial l; PV depth-4 tr-read pipeline; double-buffered global_load_lds.
// NOTE: VGPR=124 sits just under the 128 cliff (4 waves/SIMD). Any addition
// costing >=4 VGPRs drops a resident wave (R16: +8 VGPR -> 117->153us).
__global__ __launch_bounds__(256)
void attn_gqa(const unsigned short* __restrict__ kbf,
              const unsigned short* __restrict__ vbf,
              const float* __restrict__ qg, float* __restrict__ og) {
  __shared__ unsigned short k_lds[2][KVB * 128];   // 2 x 8 KB
  __shared__ unsigned short v_lds[2][KVB * 128];   // 2 x 8 KB

  const int tid = threadIdx.x;
  const int w = tid >> 6;           // 0..3 = head within KV group
  const int lane = tid & 63;
  const int l15 = lane & 15;
  const int lg = lane >> 4;

  const int bid = blockIdx.x;
  const int hkv = bid & 7;
  const int rest = bid >> 3;        // 0..95
  const int b = (rest >= 48) ? 1 : 0;
  const int slot = rest - b * 48;   // 0..47
  const int h = hkv * 4 + w;
  const float slope2 = exp2f(-0.25f * (float)(h + 1)) * LOG2E;

  // ---- per-lane staging source offsets (elems within (b,hkv) panel) ----
  int koff_e[2], voff_e[2];
#pragma unroll
  for (int i = 0; i < 2; ++i) {
    const int rk = (w * 2 + i) * 4 + lg;                   // LDS K row
    const int c = l15;                                     // 16B chunk
    const int sig = ((rk >> 2) & 3) * 8 + ((rk >> 4) & 1) * 4 + (rk & 3);
    koff_e[i] = sig * (NKV * ND) + ((c ^ (rk & 7)) * 8);
    const int e0 = (w * 2 + i) * 512 + lane * 8;           // LDS V elem
    const int sx0 = e0 & 15;
    const int vj = (e0 >> 4) & 3;
    const int vg_ = (e0 >> 6) & 3;
    const int s1 = (e0 >> 8) & 1;
    const int scv = (e0 >> 9) & 7;
    voff_e[i] = (vg_ * 8 + s1 * 4 + vj) * (NKV * ND) + scv * 16 + sx0;
  }
  const unsigned short* kpan = kbf + (size_t)b * NS * (NKV * ND) + hkv * ND;
  const unsigned short* vpan = vbf + (size_t)b * NS * (NKV * ND) + hkv * ND;

  auto stage = [&](int t, int buf) {
    const size_t eb = (size_t)(t * KVB) * (NKV * ND);
#pragma unroll
    for (int i = 0; i < 2; ++i) {
      gload16(kpan + eb + koff_e[i], &k_lds[buf][(w * 2 + i) * 512]);
      gload16(vpan + eb + voff_e[i], &v_lds[buf][(w * 2 + i) * 512]);
    }
  };

  auto run_band = [&](int q0) {
    const int qiA = q0 + l15;
    const int qiB = qiA + 16;

    // ---- Q fragments (fp32 -> bf16) ----
    u16x8 qfA[4], qfB[4];
#pragma unroll
    for (int half = 0; half < 2; ++half) {
      const int qi = half ? qiB : qiA;
      const float* qp = qg + (size_t)(b * NS + qi) * (NH * ND) + h * ND;
#pragma unroll
      for (int ks = 0; ks < 4; ++ks) {
        const int dbase = ks * 32 + lg * 8;
        float4 f0 = *(const float4*)(qp + dbase);
        float4 f1 = *(const float4*)(qp + dbase + 4);
        Frag q_;
        q_.e[0] = (__bf16)f0.x; q_.e[1] = (__bf16)f0.y;
        q_.e[2] = (__bf16)f0.z; q_.e[3] = (__bf16)f0.w;
        q_.e[4] = (__bf16)f1.x; q_.e[5] = (__bf16)f1.y;
        q_.e[6] = (__bf16)f1.z; q_.e[7] = (__bf16)f1.w;
        if (half) qfB[ks] = q_.u; else qfA[ks] = q_.u;
      }
    }

    float mA = 0.f, lA = 0.f, mB = 0.f, lB = 0.f;   // m=0: diagonal key valid
    f32x4 accA[8], accB[8];
#pragma unroll
    for (int c = 0; c < 8; ++c) {
      accA[c][0] = 0.f; accA[c][1] = 0.f; accA[c][2] = 0.f; accA[c][3] = 0.f;
      accB[c][0] = 0.f; accB[c][1] = 0.f; accB[c][2] = 0.f; accB[c][3] = 0.f;
    }

    const int t0 = (q0 >= NWIN) ? ((q0 - NWIN) >> 5) : 0;
    const int t1 = q0 >> 5;

    int cur = 0;
    stage(t1, 0);   // DESCENDING: near-diagonal tile first

    for (int t = t1; t >= t0; --t) {
      const int kvbase = t * KVB;
      if (t > t0) {
        stage(t - 1, cur ^ 1);
        asm volatile("s_waitcnt vmcnt(4)" ::: "memory");   // tile t's 4 loads done
      } else {
        asm volatile("s_waitcnt vmcnt(0)" ::: "memory");
      }
      __builtin_amdgcn_s_barrier();                        // all waves' t loads done

      // interior: masking provably inactive for all 32 rows of the band
      const bool interior = (kvbase + 31 <= q0) && (kvbase >= q0 + 31 - NWIN);

      // ---- QK^T (swapped): K-frags shared by both halves ----
      f32x4 sA[2], sB[2];
#pragma unroll
      for (int f = 0; f < 2; ++f) {
        sA[f][0] = 0.f; sA[f][1] = 0.f; sA[f][2] = 0.f; sA[f][3] = 0.f;
        sB[f][0] = 0.f; sB[f][1] = 0.f; sB[f][2] = 0.f; sB[f][3] = 0.f;
      }
      const int xo = (l15 & 7) << 4;
      __builtin_amdgcn_s_setprio(1);
#pragma unroll
      for (int ks = 0; ks < 4; ++ks) {
        const int db2 = ks * 64 + lg * 16;
        Frag qa, qb;
        qa.u = qfA[ks]; qb.u = qfB[ks];
#pragma unroll
        for (int f = 0; f < 2; ++f) {
          Frag kb;
          kb.u = *(const u16x8*)((const char*)&k_lds[cur][0] +
                                 (((f * 16 + l15) * 256 + db2) ^ xo));
          sA[f] = __builtin_amdgcn_mfma_f32_16x16x32_bf16(kb.b, qa.b, sA[f], 0, 0, 0);
          sB[f] = __builtin_amdgcn_mfma_f32_16x16x32_bf16(kb.b, qb.b, sB[f], 0, 0, 0);
        }
      }
      __builtin_amdgcn_s_setprio(0);

      // ---- lane-local online softmax per half (x = s*SCALE2 + bias - m_r) ----
      Frag pbA, pbB;
      auto softmax_half = [&](const f32x4* s, int dbse, float& m_r, float& l_r,
                              f32x4* acc, Frag& pb) {
        float x[2][4];
        if (interior) {
          const float ab2 = fmaf(-slope2, (float)dbse, -m_r);
#pragma unroll
          for (int f = 0; f < 2; ++f)
#pragma unroll
            for (int r = 0; r < 4; ++r)
              x[f][r] = fmaf(s[f][r], SCALE2,
                             fmaf(slope2, (float)(f * 4 + r), ab2));
        } else {
#pragma unroll
          for (int f = 0; f < 2; ++f)
#pragma unroll
            for (int r = 0; r < 4; ++r) {
              const int d = dbse - (f * 4 + r);           // qi - j
              const float val = fmaf(s[f][r], SCALE2, -slope2 * (float)d) - m_r;
              x[f][r] = ((unsigned)d <= (unsigned)NWIN) ? val : -1e30f;
            }
        }
        float tm = fmaxf(fmaxf(fmaxf(x[0][0], x[0][1]), x[0][2]),
                         fmaxf(fmaxf(x[0][3], x[1][0]), x[1][1]));
        tm = fmaxf(tm, fmaxf(x[1][2], x[1][3]));
        // common path: NO cross-lane ops; P <= 2^8 is bf16/fp32-safe.
        if (!__all(tm <= 8.0f)) {   // rare; wave-uniform branch
          tm = fmaxf(tm, __shfl_xor(tm, 16, 64));
          tm = fmaxf(tm, __shfl_xor(tm, 32, 64));
          const float delta = fmaxf(tm, 0.f);
          const float fac = __builtin_amdgcn_exp2f(-delta);
          m_r += delta;
          l_r *= fac;
#pragma unroll
          for (int c = 0; c < 8; ++c) acc[c] = acc[c] * fac;
#pragma unroll
          for (int f = 0; f < 2; ++f)
#pragma unroll
            for (int r = 0; r < 4; ++r) x[f][r] -= delta;
        }
        float e[8];
#pragma unroll
        for (int f = 0; f < 2; ++f)
#pragma unroll
          for (int r = 0; r < 4; ++r) {
            e[f * 4 + r] = __builtin_amdgcn_exp2f(x[f][r]);
            pb.e[f * 4 + r] = (__bf16)e[f * 4 + r];
          }
        l_r += ((e[0] + e[1]) + (e[2] + e[3])) + ((e[4] + e[5]) + (e[6] + e[7]));
      };
      softmax_half(sA, qiA - kvbase - lg * 8, mA, lA, accA, pbA);
      softmax_half(sB, qiB - kvbase - lg * 8, mB, lB, accB, pbB);

      // ---- PV (swapped), depth-4 pipelined tr-reads ----
      Frag vb4[4];
      const unsigned int vbase = (unsigned int)(uintptr_t)(&v_lds[cur][0]) + lane * 8;
#pragma unroll
      for (int cp = 0; cp < 4; ++cp) {
        const unsigned int a = vbase + cp * 1024;
        asm volatile("ds_read_b64_tr_b16 %0, %1" : "=v"(vb4[cp].w[0]) : "v"(a));
        asm volatile("ds_read_b64_tr_b16 %0, %1 offset:512" : "=v"(vb4[cp].w[1]) : "v"(a));
      }
      __builtin_amdgcn_s_setprio(1);
#pragma unroll
      for (int c = 0; c < 8; ++c) {
        if (c == 5)      asm volatile("s_waitcnt lgkmcnt(4)" ::: "memory");
        else if (c == 6) asm volatile("s_waitcnt lgkmcnt(2)" ::: "memory");
        else if (c == 7) asm volatile("s_waitcnt lgkmcnt(0)" ::: "memory");
        else             asm volatile("s_waitcnt lgkmcnt(6)" ::: "memory");
        __builtin_amdgcn_sched_barrier(0);
        accA[c] = __builtin_amdgcn_mfma_f32_16x16x32_bf16(vb4[c & 3].b, pbA.b, accA[c], 0, 0, 0);
        accB[c] = __builtin_amdgcn_mfma_f32_16x16x32_bf16(vb4[c & 3].b, pbB.b, accB[c], 0, 0, 0);
        if (c < 4) {
          const unsigned int a2 = vbase + (c + 4) * 1024;
          asm volatile("ds_read_b64_tr_b16 %0, %1" : "=v"(vb4[c].w[0]) : "v"(a2));
          asm volatile("ds_read_b64_tr_b16 %0, %1 offset:512" : "=v"(vb4[c].w[1]) : "v"(a2));
        }
      }
      __builtin_amdgcn_s_setprio(0);
      __builtin_amdgcn_sched_barrier(0);
      __builtin_amdgcn_s_barrier();      // all waves done reading buf[cur]
      cur ^= 1;
    }

    // ---- epilogue: reduce lane-partial l, then O = acc/l ----
    lA += __shfl_xor(lA, 16, 64);
    lA += __shfl_xor(lA, 32, 64);
    lB += __shfl_xor(lB, 16, 64);
    lB += __shfl_xor(lB, 32, 64);
    {
      const float inv = 1.0f / lA;
      float* op = og + (size_t)(b * NS + qiA) * (NH * ND) + h * ND + lg * 4;
#pragma unroll
      for (int c = 0; c < 8; ++c) { f32x4 o = accA[c] * inv; *(f32x4*)(op + c * 16) = o; }
    }
    {
      const float inv = 1.0f / lB;
      float* op = og + (size_t)(b * NS + qiB) * (NH * ND) + h * ND + lg * 4;
#pragma unroll
      for (int c = 0; c < 8; ++c) { f32x4 o = accB[c] * inv; *(f32x4*)(op + c * 16) = o; }
    }
  };

  if (slot < 32) {
    run_band((slot + 32) * 32);                   // long bands: 33 tiles
  } else {
    const int s = slot - 32;                      // paired shorts: (s+1)+(32-s)=33
    run_band(s * 32);
    run_band((31 - s) * 32);
  }
}

// ---------------- fallback (R6, 154us): used when ws too small ----------------
__global__ __launch_bounds__(256, 2)
void attn_fb(const float* __restrict__ qg, const float* __restrict__ kg,
             const float* __restrict__ vg, float* __restrict__ og) {
  __shared__ unsigned short k_lds[64 * 128];
  __shared__ unsigned short v_lds[64 * 128];
  const int tid = threadIdx.x;
  const int w = tid >> 6;
  const int lane = tid & 63;
  const int l15 = lane & 15;
  const int lg = lane >> 4;
  const int bid = blockIdx.x;
  const int h = bid & 31;
  const int qt = 31 - ((bid >> 5) & 31);
  const int b = bid >> 10;
  const int hkv = h >> 2;
  const float slope2 = exp2f(-0.25f * (float)(h + 1)) * LOG2E;
  const int q0 = qt * 64;
  const int qi = q0 + w * 16 + l15;
  u16x8 qf[4];
  {
    const float* qp = qg + (size_t)(b * NS + qi) * (NH * ND) + h * ND;
#pragma unroll
    for (int ks = 0; ks < 4; ++ks) {
      const int dbase = ks * 32 + lg * 8;
      float4 f0 = *(const float4*)(qp + dbase);
      float4 f1 = *(const float4*)(qp + dbase + 4);
      Frag q_;
      q_.e[0] = (__bf16)f0.x; q_.e[1] = (__bf16)f0.y;
      q_.e[2] = (__bf16)f0.z; q_.e[3] = (__bf16)f0.w;
      q_.e[4] = (__bf16)f1.x; q_.e[5] = (__bf16)f1.y;
      q_.e[6] = (__bf16)f1.z; q_.e[7] = (__bf16)f1.w;
      qf[ks] = q_.u;
    }
  }
  float m_r = -1e30f, l_r = 0.f;
  f32x4 acc[8];
#pragma unroll
  for (int c = 0; c < 8; ++c) { acc[c][0] = 0.f; acc[c][1] = 0.f; acc[c][2] = 0.f; acc[c][3] = 0.f; }
  const int srow = tid >> 5;
  const int sdb = (tid & 31) * 4;
  const int sc = sdb >> 4;
  const int sx = sdb & 15;
  float4 kreg[8], vreg[8];
  const int t0 = (q0 >= NWIN) ? ((q0 - NWIN) >> 6) : 0;
  const int t1 = q0 >> 6;
  auto load_tile = [&](int t) {
    const int kvbase = t * 64;
#pragma unroll
    for (int it = 0; it < 8; ++it) {
      const size_t go = (size_t)(b * NS + kvbase + it * 8 + srow) * (NKV * ND) + hkv * ND + sdb;
      kreg[it] = *(const float4*)(kg + go);
      vreg[it] = *(const float4*)(vg + go);
    }
  };
  load_tile(t0);
  for (int t = t0; t <= t1; ++t) {
    const int kvbase = t * 64;
    __syncthreads();
#pragma unroll
    for (int it = 0; it < 8; ++it) {
      const int row = it * 8 + srow;
      BF4 ku, vu;
      ku.b[0] = (__bf16)kreg[it].x; ku.b[1] = (__bf16)kreg[it].y;
      ku.b[2] = (__bf16)kreg[it].z; ku.b[3] = (__bf16)kreg[it].w;
      vu.b[0] = (__bf16)vreg[it].x; vu.b[1] = (__bf16)vreg[it].y;
      vu.b[2] = (__bf16)vreg[it].z; vu.b[3] = (__bf16)vreg[it].w;
      const int rk = ((row & 4) << 3) | ((row & 56) >> 1) | (row & 3);
      const int kb = (rk * 256 + sdb * 2) ^ ((rk & 7) << 4);
      *(u16x4*)((char*)k_lds + kb) = ku.u;
      const int s2 = ((row >> 5) << 1) | ((row >> 2) & 1);
      const int vi = sc * 1024 + s2 * 256 + ((row >> 3) & 3) * 64 + (row & 3) * 16 + sx;
      *(u16x4*)(&v_lds[vi]) = vu.u;
    }
    __syncthreads();
    if (t < t1) load_tile(t + 1);
    f32x4 s[4];
#pragma unroll
    for (int f = 0; f < 4; ++f) { s[f][0] = 0.f; s[f][1] = 0.f; s[f][2] = 0.f; s[f][3] = 0.f; }
    const int xo = (l15 & 7) << 4;
#pragma unroll
    for (int ks = 0; ks < 4; ++ks) {
      const int db2 = ks * 64 + lg * 16;
      Frag qa; qa.u = qf[ks];
#pragma unroll
      for (int f = 0; f < 4; ++f) {
        Frag kb;
        kb.u = *(u16x8*)((char*)k_lds + (((f * 16 + l15) * 256 + db2) ^ xo));
        s[f] = __builtin_amdgcn_mfma_f32_16x16x32_bf16(kb.b, qa.b, s[f], 0, 0, 0);
      }
    }
    const int dbse = qi - kvbase - lg * 8;
    float sv[4][4];
#pragma unroll
    for (int f = 0; f < 4; ++f) {
#pragma unroll
      for (int r = 0; r < 4; ++r) {
        const int koff = ((f & 1) << 5) + ((f >> 1) << 2) + r;
        const int d = dbse - koff;
        const float val = fmaf(s[f][r], SCALE2, -slope2 * (float)d);
        sv[f][r] = ((unsigned)d <= (unsigned)NWIN) ? val : -1e30f;
      }
    }
    float tm = fmaxf(fmaxf(sv[0][0], sv[0][1]), fmaxf(sv[0][2], sv[0][3]));
#pragma unroll
    for (int f = 1; f < 4; ++f)
      tm = fmaxf(tm, fmaxf(fmaxf(sv[f][0], sv[f][1]), fmaxf(sv[f][2], sv[f][3])));
    tm = fmaxf(tm, __shfl_xor(tm, 16, 64));
    tm = fmaxf(tm, __shfl_xor(tm, 32, 64));
    const float newm = fmaxf(m_r, tm);
    const float fac = __builtin_amdgcn_exp2f(m_r - newm);
    m_r = newm;
    float rs = 0.f;
    Frag pb0, pb1;
#pragma unroll
    for (int f = 0; f < 4; ++f) {
      float e0 = __builtin_amdgcn_exp2f(sv[f][0] - m_r);
      float e1 = __builtin_amdgcn_exp2f(sv[f][1] - m_r);
      float e2 = __builtin_amdgcn_exp2f(sv[f][2] - m_r);
      float e3 = __builtin_amdgcn_exp2f(sv[f][3] - m_r);
      rs += (e0 + e1) + (e2 + e3);
      const int base = (f >> 1) * 4;
      if (f & 1) {
        pb1.e[base + 0] = (__bf16)e0; pb1.e[base + 1] = (__bf16)e1;
        pb1.e[base + 2] = (__bf16)e2; pb1.e[base + 3] = (__bf16)e3;
      } else {
        pb0.e[base + 0] = (__bf16)e0; pb0.e[base + 1] = (__bf16)e1;
        pb0.e[base + 2] = (__bf16)e2; pb0.e[base + 3] = (__bf16)e3;
      }
    }
    rs += __shfl_xor(rs, 16, 64);
    rs += __shfl_xor(rs, 32, 64);
    l_r = l_r * fac + rs;
#pragma unroll
    for (int c = 0; c < 8; ++c) acc[c] = acc[c] * fac;
    const unsigned int vbase = (unsigned int)(uintptr_t)(&v_lds[0]) + lane * 8;
#pragma unroll
    for (int c = 0; c < 8; ++c) {
      u32x2 r0, r1, r2, r3;
      const unsigned int a = vbase + c * 2048;
      asm volatile("ds_read_b64_tr_b16 %0, %1" : "=v"(r0) : "v"(a));
      asm volatile("ds_read_b64_tr_b16 %0, %1 offset:512" : "=v"(r1) : "v"(a));
      asm volatile("ds_read_b64_tr_b16 %0, %1 offset:1024" : "=v"(r2) : "v"(a));
      asm volatile("ds_read_b64_tr_b16 %0, %1 offset:1536" : "=v"(r3) : "v"(a));
      asm volatile("s_waitcnt lgkmcnt(0)" ::: "memory");
      __builtin_amdgcn_sched_barrier(0);
      Frag vb0, vb1;
      vb0.w[0] = r0; vb0.w[1] = r1;
      vb1.w[0] = r2; vb1.w[1] = r3;
      acc[c] = __builtin_amdgcn_mfma_f32_16x16x32_bf16(vb0.b, pb0.b, acc[c], 0, 0, 0);
      acc[c] = __builtin_amdgcn_mfma_f32_16x16x32_bf16(vb1.b, pb1.b, acc[c], 0, 0, 0);
    }
  }
  const float inv = 1.0f / l_r;
  float* op = og + (size_t)(b * NS + qi) * (NH * ND) + h * ND + lg * 4;
#pragma unroll
  for (int c = 0; c < 8; ++c) { f32x4 o = acc[c] * inv; *(f32x4*)(op + c * 16) = o; }
}

extern "C" void kernel_launch(void* const* d_in, const int* in_sizes, int n_in,
                              void* d_out, int out_size, void* d_ws, size_t ws_size,
                              hipStream_t stream) {
  (void)in_sizes; (void)n_in; (void)out_size;
  const float* q = (const float*)d_in[0];
  const float* k = (const float*)d_in[1];
  const float* v = (const float*)d_in[2];
  float* out = (float*)d_out;
  const size_t kv_elems = (size_t)NB * NS * NKV * ND;       // 4M elems each
  const size_t need = 2 * kv_elems * sizeof(unsigned short); // 16 MB
  if (ws_size >= need) {
    unsigned short* kbf = (unsigned short*)d_ws;
    unsigned short* vbf = kbf + kv_elems;
    cvt_kv<<<dim3((unsigned)(kv_elems / 8 / 256)), dim3(256), 0, stream>>>(k, v, kbf, vbf);
    attn_gqa<<<dim3(NB * NKV * 48), dim3(256), 0, stream>>>(kbf, vbf, q, out);
  } else {
    attn_fb<<<dim3(NB * NH * (NS / 64)), dim3(256), 0, stream>>>(q, k, v, out);
  }
}